// Round 12
// baseline (177.864 us; speedup 1.0000x reference)
//
#include <hip/hip_runtime.h>
#include <hip/hip_bf16.h>

#define BB 2
#define SS 2048
#define HH 16
#define DD 64

#define LOG2E 1.4426950408889634f

typedef __bf16 bf16x8 __attribute__((ext_vector_type(8)));
typedef float f32x4 __attribute__((ext_vector_type(4)));
typedef float f32x16 __attribute__((ext_vector_type(16)));

__device__ __forceinline__ void gld16(const __hip_bfloat16* g, __hip_bfloat16* l) {
    __builtin_amdgcn_global_load_lds(
        (const __attribute__((address_space(1))) unsigned int*)g,
        (__attribute__((address_space(3))) unsigned int*)l, 16, 0, 0);
}

// ---------------------------------------------------------------------------
// Kernel 1: fused Q/K/V projection + V transpose + Q pre-scaling. (unchanged)
// ---------------------------------------------------------------------------
__global__ __launch_bounds__(256) void proj_kernel(
    const float* __restrict__ xq, const float* __restrict__ xk,
    const float* __restrict__ xv,
    const float* __restrict__ Wq, const float* __restrict__ bq,
    const float* __restrict__ Wk, const float* __restrict__ bk,
    const float* __restrict__ Wv, const float* __restrict__ bv,
    const float* __restrict__ inv_scale_p,
    __hip_bfloat16* __restrict__ Qp, __hip_bfloat16* __restrict__ Kp,
    __hip_bfloat16* __restrict__ Vt)
{
    __shared__ float w_lds[64][65];
    __shared__ __attribute__((aligned(16))) float x_lds[64][72];
    __shared__ __attribute__((aligned(16))) __hip_bfloat16 vt_lds[64][72];

    const int tid = threadIdx.x;
    const int bh = blockIdx.x;
    const int b = bh >> 4, h = bh & 15;
    const int s0 = blockIdx.y * 64;
    const int e = tid & 63;
    const int rg = tid >> 6;
    const float qscale = LOG2E / inv_scale_p[0];

    const float* xs[3] = {xq, xk, xv};
    const float* Ws[3] = {Wq, Wk, Wv};
    const float* Bs[3] = {bq, bk, bv};

#pragma unroll
    for (int m = 0; m < 3; ++m) {
        __syncthreads();
#pragma unroll
        for (int k = 0; k < 16; ++k) {
            const int i = tid + k * 256;
            w_lds[i & 63][i >> 6] = Ws[m][i];
        }
        {
            const int row = tid >> 2, f0 = tid & 3;
            const float* xrow = xs[m] + ((size_t)((b * SS + s0 + row) * HH + h)) * DD;
            float4* dst = (float4*)&x_lds[row][0];
            const float4* src = (const float4*)xrow;
#pragma unroll
            for (int j = 0; j < 4; ++j) dst[f0 + 4 * j] = src[f0 + 4 * j];
        }
        const float bias_e = Bs[m][e];
        __syncthreads();

        float acc[16];
#pragma unroll
        for (int it = 0; it < 16; ++it) acc[it] = bias_e;
#pragma unroll
        for (int dq = 0; dq < 16; ++dq) {
            const float w0 = w_lds[dq * 4 + 0][e];
            const float w1 = w_lds[dq * 4 + 1][e];
            const float w2 = w_lds[dq * 4 + 2][e];
            const float w3 = w_lds[dq * 4 + 3][e];
#pragma unroll
            for (int it = 0; it < 16; ++it) {
                const float4 x4 = *(const float4*)&x_lds[rg * 16 + it][dq * 4];
                acc[it] = fmaf(x4.x, w0, fmaf(x4.y, w1, fmaf(x4.z, w2, fmaf(x4.w, w3, acc[it]))));
            }
        }

        if (m == 0) {
#pragma unroll
            for (int it = 0; it < 16; ++it)
                Qp[((size_t)bh * SS + s0 + rg * 16 + it) * DD + e] =
                    __float2bfloat16(acc[it] * qscale);
        } else if (m == 1) {
#pragma unroll
            for (int it = 0; it < 16; ++it)
                Kp[((size_t)bh * SS + s0 + rg * 16 + it) * DD + e] =
                    __float2bfloat16(acc[it]);
        } else {
#pragma unroll
            for (int it = 0; it < 16; ++it)
                vt_lds[e][rg * 16 + it] = __float2bfloat16(acc[it]);
            __syncthreads();
            const int row2 = tid >> 2, f = tid & 3;
            bf16x8 vv0 = *(const bf16x8*)&vt_lds[row2][f * 16];
            bf16x8 vv1 = *(const bf16x8*)&vt_lds[row2][f * 16 + 8];
            __hip_bfloat16* dst = &Vt[((size_t)bh * DD + row2) * SS + s0 + f * 16];
            *(bf16x8*)dst = vv0;
            *(bf16x8*)(dst + 8) = vv1;
        }
    }
}

// ---------------------------------------------------------------------------
// Kernel 2: flash attention, 32x32x16 MFMA, 32 q-rows/wave, QBLK=128.
// XCD remap co-locates K/V sharers (all qt of one bh -> same XCD -> K/V
// L2-resident -> staging drain ~0).  Mask prefetched one full tile ahead
// into ping-pong registers (L3 latency hidden), still used as MFMA C-init.
// grid = 512 remapped (2 blocks/CU); block = 256 (4 waves); 1 barrier/tile.
// ---------------------------------------------------------------------------
__global__ __launch_bounds__(256, 2) void attn_kernel(
    const __hip_bfloat16* __restrict__ Qp, const __hip_bfloat16* __restrict__ Kp,
    const __hip_bfloat16* __restrict__ Vt, const float* __restrict__ mask,
    float* __restrict__ out)
{
    __shared__ __attribute__((aligned(16))) __hip_bfloat16 Kl[2][4096];
    __shared__ __attribute__((aligned(16))) __hip_bfloat16 Vl[2][4096];

    const int tid = threadIdx.x;
    const int lane = tid & 63;
    const int wave = tid >> 6;
    const int ln31 = lane & 31;
    const int hi = lane >> 5;

    // XCD-aware bijective remap (512 blocks): hw = (bh%8) + 8*qt + 128*(bh/8)
    // -> all 16 qt-blocks of one bh share hw%8 (same XCD: K/V L2-resident).
    const int hw = blockIdx.x;
    const int bh = ((hw >> 7) << 3) + (hw & 7);
    const int qt = (hw & 127) >> 3;
    const int b = bh >> 4;

    const __hip_bfloat16* Qb = Qp + (size_t)bh * SS * DD;
    const __hip_bfloat16* Kb = Kp + (size_t)bh * SS * DD;
    const __hip_bfloat16* Vtb = Vt + (size_t)bh * DD * SS;

    const int q0 = qt * 128 + wave * 32;          // wave owns q0..q0+31
    const float* mq = mask + (size_t)b * SS * SS + (size_t)(q0 + ln31) * SS;

    const int srow = lane >> 3;
    const int scol = ((lane & 7) ^ srow) * 8;     // pre-swizzled staging source
    const int rswz = (lane & 7) << 4;             // read-side XOR

    // Q fragments: B-operand, col=q=ln31, k-chunk kc: elems kc*16 + hi*8 + i
    bf16x8 qf[4];
    {
        const __hip_bfloat16* qptr = Qb + (size_t)(q0 + ln31) * DD + hi * 8;
#pragma unroll
        for (int kc = 0; kc < 4; ++kc)
            qf[kc] = *reinterpret_cast<const bf16x8*>(qptr + kc * 16);
    }

    bf16x8 ones;
#pragma unroll
    for (int i = 0; i < 8; ++i) ones[i] = (__bf16)1.0f;

    f32x16 o[2];          // C: col=d(ln31), row=q=(r&3)+8(r>>2)+4hi
    f32x16 lacc;
    float m_r = -1e30f;   // running max (log2 domain) for q = q0+ln31
#pragma unroll
    for (int r = 0; r < 16; ++r) { o[0][r] = 0.f; o[1][r] = 0.f; lacc[r] = 0.f; }

#define STAGE(bufi, t0s)                                                        \
    {                                                                           \
        _Pragma("unroll")                                                       \
        for (int cc = 0; cc < 2; ++cc) {                                        \
            const int c = wave * 2 + cc;                                        \
            const int row = c * 8 + srow;                                       \
            gld16(Kb + (size_t)((t0s) + row) * DD + scol, &Kl[bufi][c * 512]);  \
            gld16(Vtb + (size_t)row * SS + (t0s) + scol, &Vl[bufi][c * 512]);   \
        }                                                                       \
    }

#define LOADMASK(mv, t0s)                                                       \
    {                                                                           \
        _Pragma("unroll")                                                       \
        for (int nt = 0; nt < 2; ++nt)                                          \
            _Pragma("unroll")                                                   \
            for (int gi = 0; gi < 4; ++gi)                                      \
                mv[nt][gi] = *(const f32x4*)&mq[(t0s) + nt * 32 + hi * 4 + gi * 8]; \
    }

#define KFRAG(nt, kc) (*(const bf16x8*)((const char*)Kl[buf] +                  \
        (nt) * 4096 + ln31 * 128 + (((kc) * 32 + hi * 16) ^ rswz)))
#define VFRAG(dblk, kc) (*(const bf16x8*)((const char*)Vl[buf] +                \
        (dblk) * 4096 + ln31 * 128 + (((kc) * 32 + hi * 16) ^ rswz)))

    int buf = 0;
    f32x4 mvA[2][4], mvB[2][4];

    auto compute_tile = [&](const f32x4 (&mv)[2][4]) {
        // ---- QK^T (swapped), C-init = mask*log2e (prefetched regs) ----
        f32x16 s[2];
#pragma unroll
        for (int nt = 0; nt < 2; ++nt)
#pragma unroll
            for (int r = 0; r < 16; ++r)
                s[nt][r] = mv[nt][r >> 2][r & 3] * LOG2E;

        __builtin_amdgcn_s_setprio(1);
#pragma unroll
        for (int kc = 0; kc < 4; ++kc) {
            bf16x8 k0 = KFRAG(0, kc);
            bf16x8 k1 = KFRAG(1, kc);
            s[0] = __builtin_amdgcn_mfma_f32_32x32x16_bf16(k0, qf[kc], s[0], 0, 0, 0);
            s[1] = __builtin_amdgcn_mfma_f32_32x32x16_bf16(k1, qf[kc], s[1], 0, 0, 0);
        }
        __builtin_amdgcn_s_setprio(0);

        // ---- V fragments: issue DS reads now, hide under softmax ----
        bf16x8 vfr[2][4];
#pragma unroll
        for (int dblk = 0; dblk < 2; ++dblk)
#pragma unroll
            for (int kc = 0; kc < 4; ++kc)
                vfr[dblk][kc] = VFRAG(dblk, kc);

        // ---- defer-max: lane-local max + wave vote ----
        float pmax = fmaxf(s[0][0], fmaxf(s[0][1], s[0][2]));
#pragma unroll
        for (int r = 3; r < 16; r += 3)
            pmax = fmaxf(pmax, fmaxf(s[0][r], fmaxf(s[0][(r + 1) & 15], s[0][(r + 2) & 15])));
#pragma unroll
        for (int r = 0; r < 16; r += 4)
            pmax = fmaxf(pmax, fmaxf(fmaxf(s[1][r], s[1][r + 1]), fmaxf(s[1][r + 2], s[1][r + 3])));

        if (!__all(pmax - m_r <= 11.5f)) {
            float mx = fmaxf(pmax, __shfl_xor(pmax, 32));
            const float mn = fmaxf(m_r, mx);
            const float alpha = exp2f(m_r - mn);
            m_r = mn;
#pragma unroll
            for (int r = 0; r < 16; ++r) {
                const float a = __shfl(alpha, (r & 3) + 8 * (r >> 2) + 4 * hi);
                o[0][r] *= a; o[1][r] *= a; lacc[r] *= a;
            }
        }

        // ---- P = exp2(s - m) ----
#pragma unroll
        for (int nt = 0; nt < 2; ++nt)
#pragma unroll
            for (int r = 0; r < 16; ++r)
                s[nt][r] = __builtin_amdgcn_exp2f(s[nt][r] - m_r);

        // ---- P -> PV A-fragments in-register (one shfl_xor(32) per pair) ----
        bf16x8 pfa[4];
#pragma unroll
        for (int nt = 0; nt < 2; ++nt) {
            unsigned c[8];
#pragma unroll
            for (int j = 0; j < 8; ++j) {
                union { __hip_bfloat162 hh; unsigned u; } cu;
                cu.hh = __float22bfloat162_rn(make_float2(s[nt][2 * j], s[nt][2 * j + 1]));
                c[j] = cu.u;
            }
#pragma unroll
            for (int half = 0; half < 2; ++half) {
                const unsigned c0 = c[half * 4 + 0], c1 = c[half * 4 + 1];
                const unsigned c2 = c[half * 4 + 2], c3 = c[half * 4 + 3];
                const unsigned X  = hi ? c0 : c2;
                const unsigned Y  = (unsigned)__shfl_xor((int)X, 32);
                const unsigned X2 = hi ? c1 : c3;
                const unsigned Y2 = (unsigned)__shfl_xor((int)X2, 32);
                union { bf16x8 v; unsigned w[4]; } pu;
                pu.w[0] = hi ? Y : c0;
                pu.w[1] = hi ? Y2 : c1;
                pu.w[2] = hi ? c2 : Y;
                pu.w[3] = hi ? c3 : Y2;
                pfa[nt * 2 + half] = pu.v;
            }
        }

        // ---- O += P @ V ; l += P @ ones ----
        __builtin_amdgcn_s_setprio(1);
#pragma unroll
        for (int kc = 0; kc < 4; ++kc) {
            lacc = __builtin_amdgcn_mfma_f32_32x32x16_bf16(pfa[kc], ones, lacc, 0, 0, 0);
            o[0] = __builtin_amdgcn_mfma_f32_32x32x16_bf16(pfa[kc], vfr[0][kc], o[0], 0, 0, 0);
            o[1] = __builtin_amdgcn_mfma_f32_32x32x16_bf16(pfa[kc], vfr[1][kc], o[1], 0, 0, 0);
        }
        __builtin_amdgcn_s_setprio(0);
    };

    // prologue: stage tile 0 + mask tile 0
    STAGE(0, 0);
    LOADMASK(mvA, 0);
    __syncthreads();

    // two tiles per iteration (ping-pong mask regs, no copies)
    for (int t0 = 0; t0 < SS; t0 += 128) {
        // ---- tile A (t0), mask in mvA; prefetch mask t0+64 into mvB ----
        STAGE(buf ^ 1, t0 + 64);
        LOADMASK(mvB, t0 + 64);
        compute_tile(mvA);
        __syncthreads();
        buf ^= 1;

        // ---- tile B (t0+64), mask in mvB; prefetch t0+128 into mvA ----
        const bool more = (t0 + 128 < SS);
        if (more) {
            STAGE(buf ^ 1, t0 + 128);
            LOADMASK(mvA, t0 + 128);
        }
        compute_tile(mvB);
        __syncthreads();
        buf ^= 1;
    }

    // ---- epilogue: normalize and store [B,H,S,D] f32 ----
#pragma unroll
    for (int r = 0; r < 16; ++r) {
        const float inv_l = 1.0f / lacc[r];
        const int q = q0 + (r & 3) + 8 * (r >> 2) + 4 * hi;
        float* orow = out + ((size_t)bh * SS + q) * DD + ln31;
        orow[0]  = o[0][r] * inv_l;
        orow[32] = o[1][r] * inv_l;
    }
#undef STAGE
#undef LOADMASK
#undef KFRAG
#undef VFRAG
}

extern "C" void kernel_launch(void* const* d_in, const int* in_sizes, int n_in,
                              void* d_out, int out_size, void* d_ws, size_t ws_size,
                              hipStream_t stream) {
    const float* xq        = (const float*)d_in[0];
    const float* xk        = (const float*)d_in[1];
    const float* xv        = (const float*)d_in[2];
    const float* mask      = (const float*)d_in[3];
    const float* inv_scale = (const float*)d_in[4];
    const float* Wq        = (const float*)d_in[5];
    const float* bq        = (const float*)d_in[6];
    const float* Wk        = (const float*)d_in[7];
    const float* bk        = (const float*)d_in[8];
    const float* Wv        = (const float*)d_in[9];
    const float* bv        = (const float*)d_in[10];

    __hip_bfloat16* Qp = (__hip_bfloat16*)d_ws;
    __hip_bfloat16* Kp = Qp + (size_t)BB * HH * SS * DD;
    __hip_bfloat16* Vt = Kp + (size_t)BB * HH * SS * DD;
    float* out = (float*)d_out;

    proj_kernel<<<dim3(BB * HH, SS / 64), dim3(256), 0, stream>>>(
        xq, xk, xv, Wq, bq, Wk, bk, Wv, bv, inv_scale, Qp, Kp, Vt);

    attn_kernel<<<dim3(512), dim3(256), 0, stream>>>(
        Qp, Kp, Vt, mask, out);
}

// Round 13
// 124.601 us; speedup vs baseline: 1.4275x; 1.4275x over previous
//
#include <hip/hip_runtime.h>
#include <hip/hip_bf16.h>

#define BB 2
#define SS 2048
#define HH 16
#define DD 64

#define LOG2E 1.4426950408889634f

typedef __bf16 bf16x8 __attribute__((ext_vector_type(8)));
typedef float f32x4 __attribute__((ext_vector_type(4)));
typedef float f32x16 __attribute__((ext_vector_type(16)));

__device__ __forceinline__ void gld16(const __hip_bfloat16* g, __hip_bfloat16* l) {
    __builtin_amdgcn_global_load_lds(
        (const __attribute__((address_space(1))) unsigned int*)g,
        (__attribute__((address_space(3))) unsigned int*)l, 16, 0, 0);
}

// ---------------------------------------------------------------------------
// Kernel 1: fused Q/K/V projection + V transpose + Q pre-scaling. (unchanged)
// ---------------------------------------------------------------------------
__global__ __launch_bounds__(256) void proj_kernel(
    const float* __restrict__ xq, const float* __restrict__ xk,
    const float* __restrict__ xv,
    const float* __restrict__ Wq, const float* __restrict__ bq,
    const float* __restrict__ Wk, const float* __restrict__ bk,
    const float* __restrict__ Wv, const float* __restrict__ bv,
    const float* __restrict__ inv_scale_p,
    __hip_bfloat16* __restrict__ Qp, __hip_bfloat16* __restrict__ Kp,
    __hip_bfloat16* __restrict__ Vt)
{
    __shared__ float w_lds[64][65];
    __shared__ __attribute__((aligned(16))) float x_lds[64][72];
    __shared__ __attribute__((aligned(16))) __hip_bfloat16 vt_lds[64][72];

    const int tid = threadIdx.x;
    const int bh = blockIdx.x;
    const int b = bh >> 4, h = bh & 15;
    const int s0 = blockIdx.y * 64;
    const int e = tid & 63;
    const int rg = tid >> 6;
    const float qscale = LOG2E / inv_scale_p[0];

    const float* xs[3] = {xq, xk, xv};
    const float* Ws[3] = {Wq, Wk, Wv};
    const float* Bs[3] = {bq, bk, bv};

#pragma unroll
    for (int m = 0; m < 3; ++m) {
        __syncthreads();
#pragma unroll
        for (int k = 0; k < 16; ++k) {
            const int i = tid + k * 256;
            w_lds[i & 63][i >> 6] = Ws[m][i];
        }
        {
            const int row = tid >> 2, f0 = tid & 3;
            const float* xrow = xs[m] + ((size_t)((b * SS + s0 + row) * HH + h)) * DD;
            float4* dst = (float4*)&x_lds[row][0];
            const float4* src = (const float4*)xrow;
#pragma unroll
            for (int j = 0; j < 4; ++j) dst[f0 + 4 * j] = src[f0 + 4 * j];
        }
        const float bias_e = Bs[m][e];
        __syncthreads();

        float acc[16];
#pragma unroll
        for (int it = 0; it < 16; ++it) acc[it] = bias_e;
#pragma unroll
        for (int dq = 0; dq < 16; ++dq) {
            const float w0 = w_lds[dq * 4 + 0][e];
            const float w1 = w_lds[dq * 4 + 1][e];
            const float w2 = w_lds[dq * 4 + 2][e];
            const float w3 = w_lds[dq * 4 + 3][e];
#pragma unroll
            for (int it = 0; it < 16; ++it) {
                const float4 x4 = *(const float4*)&x_lds[rg * 16 + it][dq * 4];
                acc[it] = fmaf(x4.x, w0, fmaf(x4.y, w1, fmaf(x4.z, w2, fmaf(x4.w, w3, acc[it]))));
            }
        }

        if (m == 0) {
#pragma unroll
            for (int it = 0; it < 16; ++it)
                Qp[((size_t)bh * SS + s0 + rg * 16 + it) * DD + e] =
                    __float2bfloat16(acc[it] * qscale);
        } else if (m == 1) {
#pragma unroll
            for (int it = 0; it < 16; ++it)
                Kp[((size_t)bh * SS + s0 + rg * 16 + it) * DD + e] =
                    __float2bfloat16(acc[it]);
        } else {
#pragma unroll
            for (int it = 0; it < 16; ++it)
                vt_lds[e][rg * 16 + it] = __float2bfloat16(acc[it]);
            __syncthreads();
            const int row2 = tid >> 2, f = tid & 3;
            bf16x8 vv0 = *(const bf16x8*)&vt_lds[row2][f * 16];
            bf16x8 vv1 = *(const bf16x8*)&vt_lds[row2][f * 16 + 8];
            __hip_bfloat16* dst = &Vt[((size_t)bh * DD + row2) * SS + s0 + f * 16];
            *(bf16x8*)dst = vv0;
            *(bf16x8*)(dst + 8) = vv1;
        }
    }
}

// ---------------------------------------------------------------------------
// Kernel 2: flash attention, 32x32x16 MFMA, 32 q-rows/wave, QBLK=128.
// Identical to the round-11 kernel (103us, VGPR 96, no scratch) EXCEPT the
// block remap now co-locates K/V sharers: hw = (bh%8) + 8*qt + 128*(bh/8)
// -> all 16 qt-blocks of one bh on one XCD -> K/V panels L2-resident ->
// staging vmcnt drain at L2 latency.
// grid = 512 remapped (2 blocks/CU); block = 256 (4 waves); 1 barrier/tile.
// ---------------------------------------------------------------------------
__global__ __launch_bounds__(256, 2) void attn_kernel(
    const __hip_bfloat16* __restrict__ Qp, const __hip_bfloat16* __restrict__ Kp,
    const __hip_bfloat16* __restrict__ Vt, const float* __restrict__ mask,
    float* __restrict__ out)
{
    __shared__ __attribute__((aligned(16))) __hip_bfloat16 Kl[2][4096];
    __shared__ __attribute__((aligned(16))) __hip_bfloat16 Vl[2][4096];

    const int tid = threadIdx.x;
    const int lane = tid & 63;
    const int wave = tid >> 6;
    const int ln31 = lane & 31;
    const int hi = lane >> 5;

    // K/V-sharing XCD remap (bijective on [0,512))
    const int hw = blockIdx.x;
    const int bh = ((hw >> 7) << 3) + (hw & 7);
    const int qt = (hw & 127) >> 3;
    const int b = bh >> 4;

    const __hip_bfloat16* Qb = Qp + (size_t)bh * SS * DD;
    const __hip_bfloat16* Kb = Kp + (size_t)bh * SS * DD;
    const __hip_bfloat16* Vtb = Vt + (size_t)bh * DD * SS;

    const int q0 = qt * 128 + wave * 32;          // wave owns q0..q0+31
    const float* mq = mask + (size_t)b * SS * SS + (size_t)(q0 + ln31) * SS;

    const int srow = lane >> 3;
    const int scol = ((lane & 7) ^ srow) * 8;     // pre-swizzled staging source
    const int rswz = (lane & 7) << 4;             // read-side XOR

    // Q fragments: B-operand, col=q=ln31, k-chunk kc: elems kc*16 + hi*8 + i
    bf16x8 qf[4];
    {
        const __hip_bfloat16* qptr = Qb + (size_t)(q0 + ln31) * DD + hi * 8;
#pragma unroll
        for (int kc = 0; kc < 4; ++kc)
            qf[kc] = *reinterpret_cast<const bf16x8*>(qptr + kc * 16);
    }

    bf16x8 ones;
#pragma unroll
    for (int i = 0; i < 8; ++i) ones[i] = (__bf16)1.0f;

    f32x16 o[2];          // C: col=d(ln31), row=q=(r&3)+8(r>>2)+4hi
    f32x16 lacc;
    float m_r = -1e30f;   // running max (log2 domain) for q = q0+ln31
#pragma unroll
    for (int r = 0; r < 16; ++r) { o[0][r] = 0.f; o[1][r] = 0.f; lacc[r] = 0.f; }

#define STAGE(bufi, t0s)                                                        \
    {                                                                           \
        _Pragma("unroll")                                                       \
        for (int cc = 0; cc < 2; ++cc) {                                        \
            const int c = wave * 2 + cc;                                        \
            const int row = c * 8 + srow;                                       \
            gld16(Kb + (size_t)((t0s) + row) * DD + scol, &Kl[bufi][c * 512]);  \
            gld16(Vtb + (size_t)row * SS + (t0s) + scol, &Vl[bufi][c * 512]);   \
        }                                                                       \
    }

#define KFRAG(nt, kc) (*(const bf16x8*)((const char*)Kl[buf] +                  \
        (nt) * 4096 + ln31 * 128 + (((kc) * 32 + hi * 16) ^ rswz)))
#define VFRAG(dblk, kc) (*(const bf16x8*)((const char*)Vl[buf] +                \
        (dblk) * 4096 + ln31 * 128 + (((kc) * 32 + hi * 16) ^ rswz)))

    STAGE(0, 0);
    __syncthreads();

    int buf = 0;
    for (int t0 = 0; t0 < SS; t0 += 64) {
        const bool has_next = (t0 + 64 < SS);

        // ---- mask loads (C-init values) ----
        f32x4 mv[2][4];
#pragma unroll
        for (int nt = 0; nt < 2; ++nt)
#pragma unroll
            for (int gi = 0; gi < 4; ++gi)
                mv[nt][gi] = *(const f32x4*)&mq[t0 + nt * 32 + hi * 4 + gi * 8];

        if (has_next) STAGE(buf ^ 1, t0 + 64);

        // ---- QK^T (swapped): C col=q(ln31), row=t=nt*32+(r&3)+8(r>>2)+4hi ----
        f32x16 s[2];
#pragma unroll
        for (int nt = 0; nt < 2; ++nt)
#pragma unroll
            for (int r = 0; r < 16; ++r)
                s[nt][r] = mv[nt][r >> 2][r & 3] * LOG2E;

        __builtin_amdgcn_s_setprio(1);
#pragma unroll
        for (int kc = 0; kc < 4; ++kc) {
            bf16x8 k0 = KFRAG(0, kc);
            bf16x8 k1 = KFRAG(1, kc);
            s[0] = __builtin_amdgcn_mfma_f32_32x32x16_bf16(k0, qf[kc], s[0], 0, 0, 0);
            s[1] = __builtin_amdgcn_mfma_f32_32x32x16_bf16(k1, qf[kc], s[1], 0, 0, 0);
        }
        __builtin_amdgcn_s_setprio(0);

        // ---- V fragments: issue DS reads now, hide under softmax ----
        bf16x8 vfr[2][4];
#pragma unroll
        for (int dblk = 0; dblk < 2; ++dblk)
#pragma unroll
            for (int kc = 0; kc < 4; ++kc)
                vfr[dblk][kc] = VFRAG(dblk, kc);

        // ---- defer-max: lane-local max over 32 vals + wave vote ----
        float pmax = fmaxf(s[0][0], fmaxf(s[0][1], s[0][2]));
#pragma unroll
        for (int r = 3; r < 16; r += 3)
            pmax = fmaxf(pmax, fmaxf(s[0][r], fmaxf(s[0][(r + 1) & 15], s[0][(r + 2) & 15])));
#pragma unroll
        for (int r = 0; r < 16; r += 4)
            pmax = fmaxf(pmax, fmaxf(fmaxf(s[1][r], s[1][r + 1]), fmaxf(s[1][r + 2], s[1][r + 3])));

        if (!__all(pmax - m_r <= 11.5f)) {
            // slow path (rare): full row-max (half-exchange) + rescale state
            float mx = fmaxf(pmax, __shfl_xor(pmax, 32));
            const float mn = fmaxf(m_r, mx);
            const float alpha = exp2f(m_r - mn);
            m_r = mn;
#pragma unroll
            for (int r = 0; r < 16; ++r) {
                const float a = __shfl(alpha, (r & 3) + 8 * (r >> 2) + 4 * hi);
                o[0][r] *= a; o[1][r] *= a; lacc[r] *= a;
            }
        }

        // ---- P = exp2(s - m) in place ----
#pragma unroll
        for (int nt = 0; nt < 2; ++nt)
#pragma unroll
            for (int r = 0; r < 16; ++r)
                s[nt][r] = __builtin_amdgcn_exp2f(s[nt][r] - m_r);

        // ---- P -> PV A-fragments in-register (one shfl_xor(32) per pair) ----
        bf16x8 pfa[4];
#pragma unroll
        for (int nt = 0; nt < 2; ++nt) {
            unsigned c[8];
#pragma unroll
            for (int j = 0; j < 8; ++j) {
                union { __hip_bfloat162 hh; unsigned u; } cu;
                cu.hh = __float22bfloat162_rn(make_float2(s[nt][2 * j], s[nt][2 * j + 1]));
                c[j] = cu.u;
            }
#pragma unroll
            for (int half = 0; half < 2; ++half) {
                const unsigned c0 = c[half * 4 + 0], c1 = c[half * 4 + 1];
                const unsigned c2 = c[half * 4 + 2], c3 = c[half * 4 + 3];
                const unsigned X  = hi ? c0 : c2;
                const unsigned Y  = (unsigned)__shfl_xor((int)X, 32);
                const unsigned X2 = hi ? c1 : c3;
                const unsigned Y2 = (unsigned)__shfl_xor((int)X2, 32);
                union { bf16x8 v; unsigned w[4]; } pu;
                pu.w[0] = hi ? Y : c0;
                pu.w[1] = hi ? Y2 : c1;
                pu.w[2] = hi ? c2 : Y;
                pu.w[3] = hi ? c3 : Y2;
                pfa[nt * 2 + half] = pu.v;
            }
        }

        // ---- O += P @ V ; l += P @ ones.  C: col=d(ln31), row=q ----
        __builtin_amdgcn_s_setprio(1);
#pragma unroll
        for (int kc = 0; kc < 4; ++kc) {
            lacc = __builtin_amdgcn_mfma_f32_32x32x16_bf16(pfa[kc], ones, lacc, 0, 0, 0);
            o[0] = __builtin_amdgcn_mfma_f32_32x32x16_bf16(pfa[kc], vfr[0][kc], o[0], 0, 0, 0);
            o[1] = __builtin_amdgcn_mfma_f32_32x32x16_bf16(pfa[kc], vfr[1][kc], o[1], 0, 0, 0);
        }
        __builtin_amdgcn_s_setprio(0);

        __syncthreads();
        buf ^= 1;
    }

    // ---- epilogue: normalize and store [B,H,S,D] f32 (coalesced over d) ----
#pragma unroll
    for (int r = 0; r < 16; ++r) {
        const float inv_l = 1.0f / lacc[r];
        const int q = q0 + (r & 3) + 8 * (r >> 2) + 4 * hi;
        float* orow = out + ((size_t)bh * SS + q) * DD + ln31;
        orow[0]  = o[0][r] * inv_l;
        orow[32] = o[1][r] * inv_l;
    }
#undef STAGE
#undef KFRAG
#undef VFRAG
}

extern "C" void kernel_launch(void* const* d_in, const int* in_sizes, int n_in,
                              void* d_out, int out_size, void* d_ws, size_t ws_size,
                              hipStream_t stream) {
    const float* xq        = (const float*)d_in[0];
    const float* xk        = (const float*)d_in[1];
    const float* xv        = (const float*)d_in[2];
    const float* mask      = (const float*)d_in[3];
    const float* inv_scale = (const float*)d_in[4];
    const float* Wq        = (const float*)d_in[5];
    const float* bq        = (const float*)d_in[6];
    const float* Wk        = (const float*)d_in[7];
    const float* bk        = (const float*)d_in[8];
    const float* Wv        = (const float*)d_in[9];
    const float* bv        = (const float*)d_in[10];

    __hip_bfloat16* Qp = (__hip_bfloat16*)d_ws;
    __hip_bfloat16* Kp = Qp + (size_t)BB * HH * SS * DD;
    __hip_bfloat16* Vt = Kp + (size_t)BB * HH * SS * DD;
    float* out = (float*)d_out;

    proj_kernel<<<dim3(BB * HH, SS / 64), dim3(256), 0, stream>>>(
        xq, xk, xv, Wq, bq, Wk, bk, Wv, bv, inv_scale, Qp, Kp, Vt);

    attn_kernel<<<dim3(512), dim3(256), 0, stream>>>(
        Qp, Kp, Vt, mask, out);
}